// Round 1
// baseline (378.161 us; speedup 1.0000x reference)
//
#include <hip/hip_runtime.h>

#define NB 256          // histogram bins
#define NCH 48          // B*C = 16*3
#define HW (1024*1024)  // elements per channel
#define BLOCKS_PER_CH 64
#define THREADS 256

__device__ __forceinline__ int quant255(float v) {
    v = fminf(fmaxf(v, 0.0f), 1.0f);
    int q = (int)(v * 255.0f);     // float32 mul + trunc, same as jnp
    q = q < 0 ? 0 : q;
    q = q > 255 ? 255 : q;
    return q;
}

// ---------------- Kernel 1: per-channel histogram ----------------
__global__ __launch_bounds__(THREADS) void hist_kernel(
    const float* __restrict__ x, unsigned int* __restrict__ ghist) {
    __shared__ unsigned int lh[NB];
    const int t = threadIdx.x;
    lh[t] = 0u;
    __syncthreads();

    const int ch  = blockIdx.x / BLOCKS_PER_CH;
    const int blk = blockIdx.x % BLOCKS_PER_CH;

    const float4* xp = (const float4*)(x + (size_t)ch * HW);
    const int n4_per_block = (HW / 4) / BLOCKS_PER_CH;   // 4096
    const int base = blk * n4_per_block;

    for (int i = base + t; i < base + n4_per_block; i += THREADS) {
        float4 v = xp[i];
        atomicAdd(&lh[quant255(v.x)], 1u);
        atomicAdd(&lh[quant255(v.y)], 1u);
        atomicAdd(&lh[quant255(v.z)], 1u);
        atomicAdd(&lh[quant255(v.w)], 1u);
    }
    __syncthreads();
    if (lh[t] != 0u)
        atomicAdd(&ghist[ch * NB + t], lh[t]);
}

// ---------------- Kernel 2: per-channel CDF ----------------
__global__ __launch_bounds__(THREADS) void cdf_kernel(
    const unsigned int* __restrict__ ghist, float* __restrict__ cdf) {
    __shared__ float s[NB];
    const int c = blockIdx.x, t = threadIdx.x;
    s[t] = (float)ghist[c * NB + t];
    __syncthreads();
    // Hillis-Steele inclusive scan; all partials are integers < 2^24 -> exact
    for (int off = 1; off < NB; off <<= 1) {
        float add = (t >= off) ? s[t - off] : 0.0f;
        __syncthreads();
        s[t] += add;
        __syncthreads();
    }
    float total = s[NB - 1];
    cdf[c * NB + t] = s[t] / fmaxf(total, 1.0f);
}

// ---------------- Kernel 3: remap through CDF ----------------
__global__ __launch_bounds__(THREADS) void remap_kernel(
    const float* __restrict__ x, const float* __restrict__ cdf,
    float* __restrict__ y) {
    __shared__ float lc[NB];
    const int t = threadIdx.x;
    const int ch  = blockIdx.x / BLOCKS_PER_CH;
    const int blk = blockIdx.x % BLOCKS_PER_CH;
    lc[t] = cdf[ch * NB + t];
    __syncthreads();

    const float4* xp = (const float4*)(x + (size_t)ch * HW);
    float4*       yp = (float4*)      (y + (size_t)ch * HW);
    const int n4_per_block = (HW / 4) / BLOCKS_PER_CH;
    const int base = blk * n4_per_block;

    for (int i = base + t; i < base + n4_per_block; i += THREADS) {
        float4 v = xp[i];
        float4 o;
        o.x = lc[quant255(v.x)];
        o.y = lc[quant255(v.y)];
        o.z = lc[quant255(v.z)];
        o.w = lc[quant255(v.w)];
        yp[i] = o;
    }
}

extern "C" void kernel_launch(void* const* d_in, const int* in_sizes, int n_in,
                              void* d_out, int out_size, void* d_ws, size_t ws_size,
                              hipStream_t stream) {
    const float* x = (const float*)d_in[0];
    float* y = (float*)d_out;

    unsigned int* ghist = (unsigned int*)d_ws;
    float* cdf = (float*)((char*)d_ws + NCH * NB * sizeof(unsigned int));

    // ws is poisoned to 0xAA before every launch -> zero the histogram region
    hipMemsetAsync(ghist, 0, NCH * NB * sizeof(unsigned int), stream);

    hist_kernel <<<NCH * BLOCKS_PER_CH, THREADS, 0, stream>>>(x, ghist);
    cdf_kernel  <<<NCH,                 THREADS, 0, stream>>>(ghist, cdf);
    remap_kernel<<<NCH * BLOCKS_PER_CH, THREADS, 0, stream>>>(x, cdf, y);
}

// Round 2
// 368.574 us; speedup vs baseline: 1.0260x; 1.0260x over previous
//
#include <hip/hip_runtime.h>

#define NB 256          // histogram bins
#define NCH 48          // B*C = 16*3
#define HW (1024*1024)  // elements per channel
#define BLOCKS_PER_CH 64
#define THREADS 256
#define NWAVE (THREADS / 64)

__device__ __forceinline__ int quant255(float v) {
    v = fminf(fmaxf(v, 0.0f), 1.0f);
    int q = (int)(v * 255.0f);     // float32 mul + trunc, same as jnp
    q = q < 0 ? 0 : q;
    q = q > 255 ? 255 : q;
    return q;
}

// ---- Kernel 1: quantize to u8 (cached in ws) + per-channel histogram ----
// Per-wave replicated LDS histograms: inter-wave same-address atomic
// contention eliminated; intra-wave random bins over 32 banks avg ~2-way
// (free on gfx950).
__global__ __launch_bounds__(THREADS) void hist_quant_kernel(
    const float* __restrict__ x, unsigned int* __restrict__ ghist,
    unsigned char* __restrict__ q) {
    __shared__ unsigned int lh[NWAVE][NB];
    const int t = threadIdx.x;
    const int w = t >> 6;
    for (int i = t; i < NWAVE * NB; i += THREADS)
        ((unsigned int*)lh)[i] = 0u;
    __syncthreads();

    const int ch  = blockIdx.x / BLOCKS_PER_CH;
    const int blk = blockIdx.x % BLOCKS_PER_CH;

    const float4* xp = (const float4*)(x + (size_t)ch * HW);
    uchar4*       qp = (uchar4*)      (q + (size_t)ch * HW);
    const int n4 = (HW / 4) / BLOCKS_PER_CH;   // 4096
    const int base = blk * n4;

    for (int i = base + t; i < base + n4; i += THREADS) {
        float4 v = xp[i];
        int q0 = quant255(v.x), q1 = quant255(v.y);
        int q2 = quant255(v.z), q3 = quant255(v.w);
        atomicAdd(&lh[w][q0], 1u);
        atomicAdd(&lh[w][q1], 1u);
        atomicAdd(&lh[w][q2], 1u);
        atomicAdd(&lh[w][q3], 1u);
        qp[i] = make_uchar4((unsigned char)q0, (unsigned char)q1,
                            (unsigned char)q2, (unsigned char)q3);
    }
    __syncthreads();
    unsigned int s = 0;
    for (int r = 0; r < NWAVE; ++r) s += lh[r][t];
    if (s != 0u)
        atomicAdd(&ghist[ch * NB + t], s);
}

// ---------------- Kernel 2: per-channel CDF ----------------
__global__ __launch_bounds__(THREADS) void cdf_kernel(
    const unsigned int* __restrict__ ghist, float* __restrict__ cdf) {
    __shared__ float s[NB];
    const int c = blockIdx.x, t = threadIdx.x;
    s[t] = (float)ghist[c * NB + t];
    __syncthreads();
    // Hillis-Steele inclusive scan; partials are integers < 2^24 -> exact fp32
    for (int off = 1; off < NB; off <<= 1) {
        float add = (t >= off) ? s[t - off] : 0.0f;
        __syncthreads();
        s[t] += add;
        __syncthreads();
    }
    float total = s[NB - 1];
    cdf[c * NB + t] = s[t] / fmaxf(total, 1.0f);
}

// ---- Kernel 3: remap via cached u8 values through CDF LUT ----
__global__ __launch_bounds__(THREADS) void remap_kernel(
    const unsigned char* __restrict__ q, const float* __restrict__ cdf,
    float* __restrict__ y) {
    __shared__ float lc[NB];
    const int t = threadIdx.x;
    const int ch  = blockIdx.x / BLOCKS_PER_CH;
    const int blk = blockIdx.x % BLOCKS_PER_CH;
    lc[t] = cdf[ch * NB + t];
    __syncthreads();

    const uchar4* qp = (const uchar4*)(q + (size_t)ch * HW);
    float4*       yp = (float4*)      (y + (size_t)ch * HW);
    const int n4 = (HW / 4) / BLOCKS_PER_CH;
    const int base = blk * n4;

    for (int i = base + t; i < base + n4; i += THREADS) {
        uchar4 v = qp[i];
        float4 o = make_float4(lc[v.x], lc[v.y], lc[v.z], lc[v.w]);
        yp[i] = o;
    }
}

extern "C" void kernel_launch(void* const* d_in, const int* in_sizes, int n_in,
                              void* d_out, int out_size, void* d_ws, size_t ws_size,
                              hipStream_t stream) {
    const float* x = (const float*)d_in[0];
    float* y = (float*)d_out;

    unsigned int*  ghist = (unsigned int*)d_ws;
    float*         cdf   = (float*)((char*)d_ws + NCH * NB * sizeof(unsigned int));
    unsigned char* q     = (unsigned char*)((char*)d_ws + 256 * 1024); // 48 MB region

    // ws is poisoned to 0xAA before every launch -> zero the histogram region
    hipMemsetAsync(ghist, 0, NCH * NB * sizeof(unsigned int), stream);

    hist_quant_kernel<<<NCH * BLOCKS_PER_CH, THREADS, 0, stream>>>(x, ghist, q);
    cdf_kernel       <<<NCH,                 THREADS, 0, stream>>>(ghist, cdf);
    remap_kernel     <<<NCH * BLOCKS_PER_CH, THREADS, 0, stream>>>(q, cdf, y);
}